// Round 3
// baseline (714.119 us; speedup 1.0000x reference)
//
#include <hip/hip_runtime.h>

// self_attention: B=4, C=512, C8=64, N=64*64=4096
// R2: k_attn is L2-BW bound on hv2 re-reads (traffic = blocks x Ct x N x 2B).
//   k_attn: j-tile 128, c-tile 256 -> 256 blocks; hv2 L2 traffic 512MB (vs 2GB R1).
//           S duplicated x2 across c-halves (cheap); per-wave 56 MFMA/iter per barrier.
//   k_fg: back to n-tile 64 (256 blocks) - halves W re-read traffic.
//   k_hv: retiled to 128c x 128i per block (512 blocks) - halves L2 traffic.

#define Bq 4
#define Cq 512
#define Nq 4096

typedef __attribute__((ext_vector_type(8))) short bf16x8;
typedef __attribute__((ext_vector_type(4))) short bf16x4;
typedef __attribute__((ext_vector_type(4))) float f32x4;

__device__ __forceinline__ short f2bf(float f) {
  unsigned u = __float_as_uint(f);
  u += 0x7fffu + ((u >> 16) & 1u);   // RNE
  return (short)(u >> 16);
}
__device__ __forceinline__ float bf2f(short h) {
  return __uint_as_float(((unsigned)(unsigned short)h) << 16);
}

#define MFMA16(A, B, C) __builtin_amdgcn_mfma_f32_16x16x32_bf16((A), (B), (C), 0, 0, 0)

// ---------------- K_prepw: W splits ----------------
__global__ __launch_bounds__(256) void k_prepw(
    const float* __restrict__ Wf, const float* __restrict__ Wg,
    const float* __restrict__ Wh,
    short* __restrict__ whi, short* __restrict__ wlo, short* __restrict__ whb) {
  int gid = blockIdx.x * 256 + threadIdx.x;  // 0..262143
  if (gid < 128 * 512) {
    int row = gid >> 9;
    float v = (row < 64) ? Wf[gid] : Wg[gid - 32768];
    short h = f2bf(v);
    whi[gid] = h;
    wlo[gid] = f2bf(v - bf2f(h));
  }
  whb[gid] = f2bf(Wh[gid]);
}

// ---------------- K_xpose: x (B,C,N) fp32 -> XT (B,N,C) bf16 hi/lo ----------------
__global__ __launch_bounds__(256) void k_xpose(
    const float* __restrict__ x, short* __restrict__ xthi, short* __restrict__ xtlo) {
  int b = blockIdx.z, c0 = blockIdx.y * 64, n0 = blockIdx.x * 64;
  __shared__ float tile[64][65];
  int t = threadIdx.x;
  int l = t & 15, g = t >> 4;
  const float* xp = x + ((size_t)b * Cq + c0) * Nq + n0;
#pragma unroll
  for (int e = 0; e < 4; e++) {
    int cl = g + e * 16;
    float4 v = *(const float4*)(xp + (size_t)cl * Nq + l * 4);
    tile[cl][l * 4 + 0] = v.x; tile[cl][l * 4 + 1] = v.y;
    tile[cl][l * 4 + 2] = v.z; tile[cl][l * 4 + 3] = v.w;
  }
  __syncthreads();
#pragma unroll
  for (int e = 0; e < 4; e++) {
    int nl = g + e * 16;
    short hi[4], lo[4];
#pragma unroll
    for (int qq = 0; qq < 4; qq++) {
      float v = tile[l * 4 + qq][nl];
      hi[qq] = f2bf(v);
      lo[qq] = f2bf(v - bf2f(hi[qq]));
    }
    size_t off = ((size_t)b * Nq + n0 + nl) * Cq + c0 + l * 4;
    *(short4*)(xthi + off) = make_short4(hi[0], hi[1], hi[2], hi[3]);
    *(short4*)(xtlo + off) = make_short4(lo[0], lo[1], lo[2], lo[3]);
  }
}

// ---------------- K_fg: f,g GEMM (split-bf16, 3 MFMAs); n-tile 64, 256 blocks ----
__global__ __launch_bounds__(512) void k_fg(
    const short* __restrict__ xthi, const short* __restrict__ xtlo,
    const short* __restrict__ whi, const short* __restrict__ wlo,
    const float* __restrict__ bfv, const float* __restrict__ bgv,
    short* __restrict__ fhi, short* __restrict__ flo,
    short* __restrict__ ghi, short* __restrict__ glo) {
  int b = blockIdx.y, n0 = blockIdx.x * 64;
  int t = threadIdx.x, w = t >> 6, lane = t & 63, l15 = lane & 15, q = lane >> 4;
  int wr = w & 3, wh = w >> 2;  // row group / o-half (0=f,1=g)
  const short* ah = xthi + ((size_t)b * Nq + n0 + wr * 16 + l15) * Cq;
  const short* al = xtlo + ((size_t)b * Nq + n0 + wr * 16 + l15) * Cq;
  f32x4 z = {0.f, 0.f, 0.f, 0.f};
  f32x4 acc[4] = {z, z, z, z};
  for (int ks = 0; ks < 16; ks++) {
    bf16x8 Ahi = *(const bf16x8*)(ah + ks * 32 + q * 8);
    bf16x8 Alo = *(const bf16x8*)(al + ks * 32 + q * 8);
#pragma unroll
    for (int os = 0; os < 4; os++) {
      int o = wh * 64 + os * 16 + l15;
      bf16x8 Bhi = *(const bf16x8*)(whi + o * 512 + ks * 32 + q * 8);
      bf16x8 Blo = *(const bf16x8*)(wlo + o * 512 + ks * 32 + q * 8);
      acc[os] = MFMA16(Alo, Bhi, acc[os]);
      acc[os] = MFMA16(Ahi, Blo, acc[os]);
      acc[os] = MFMA16(Ahi, Bhi, acc[os]);
    }
  }
#pragma unroll
  for (int os = 0; os < 4; os++) {
#pragma unroll
    for (int r = 0; r < 4; r++) {
      int og = wh * 64 + os * 16 + l15;
      int n = n0 + wr * 16 + q * 4 + r;
      float v = acc[os][r];
      if (wh == 0) {
        v += bfv[og];
        size_t off = ((size_t)b * Nq + n) * 64 + og;
        short h = f2bf(v);
        fhi[off] = h; flo[off] = f2bf(v - bf2f(h));
      } else {
        int o2 = og - 64;
        v += bgv[o2];
        size_t off = ((size_t)b * Nq + n) * 64 + o2;
        short h = f2bf(v);
        ghi[off] = h; glo[off] = f2bf(v - bf2f(h));
      }
    }
  }
}

// ---------------- K_stats: partial l_i = sum_j exp(S[i,j]) over a 1024-j chunk ----
__global__ __launch_bounds__(512) void k_stats(
    const short* __restrict__ fhi, const short* __restrict__ flo,
    const short* __restrict__ ghi, const short* __restrict__ glo,
    float* __restrict__ lsum) {
  int jc = blockIdx.x * 1024, i0 = blockIdx.y * 64, b = blockIdx.z;
  int t = threadIdx.x, w = t >> 6, lane = t & 63, l15 = lane & 15, q = lane >> 4;
  int wr = w & 3, jh = w >> 2;
  const short* fh = fhi + ((size_t)b * Nq + i0 + wr * 16 + l15) * 64;
  const short* fl = flo + ((size_t)b * Nq + i0 + wr * 16 + l15) * 64;
  bf16x8 Ahi[2], Alo[2];
  Ahi[0] = *(const bf16x8*)(fh + q * 8);
  Ahi[1] = *(const bf16x8*)(fh + 32 + q * 8);
  Alo[0] = *(const bf16x8*)(fl + q * 8);
  Alo[1] = *(const bf16x8*)(fl + 32 + q * 8);
  float ls[4] = {0.f, 0.f, 0.f, 0.f};
  for (int jt = 0; jt < 8; jt++) {
    int jb = jc + jt * 128 + jh * 64;
#pragma unroll
    for (int js = 0; js < 4; js++) {
      int j = jb + js * 16 + l15;
      const short* gh = ghi + ((size_t)b * Nq + j) * 64;
      const short* gl = glo + ((size_t)b * Nq + j) * 64;
      f32x4 sh = {0.f, 0.f, 0.f, 0.f};
      f32x4 sl = {0.f, 0.f, 0.f, 0.f};
#pragma unroll
      for (int ss = 0; ss < 2; ss++) {
        bf16x8 Bhi = *(const bf16x8*)(gh + ss * 32 + q * 8);
        bf16x8 Blo = *(const bf16x8*)(gl + ss * 32 + q * 8);
        sl = MFMA16(Alo[ss], Bhi, sl);
        sl = MFMA16(Ahi[ss], Blo, sl);
        sh = MFMA16(Ahi[ss], Bhi, sh);
      }
      ls[0] += __expf(sh[0] + sl[0]); ls[1] += __expf(sh[1] + sl[1]);
      ls[2] += __expf(sh[2] + sl[2]); ls[3] += __expf(sh[3] + sl[3]);
    }
  }
#pragma unroll
  for (int m = 1; m < 16; m <<= 1) {
    ls[0] += __shfl_xor(ls[0], m, 64);
    ls[1] += __shfl_xor(ls[1], m, 64);
    ls[2] += __shfl_xor(ls[2], m, 64);
    ls[3] += __shfl_xor(ls[3], m, 64);
  }
  __shared__ float part[2][64];
  if (l15 == 0) {
#pragma unroll
    for (int r = 0; r < 4; r++) part[jh][wr * 16 + q * 4 + r] = ls[r];
  }
  __syncthreads();
  if (t < 64) {
    atomicAdd(&lsum[(size_t)b * Nq + i0 + t], part[0][t] + part[1][t]);
  }
}

// ---------------- K_hv: hv2[b][c][i] = bf16((Wh.x + bh) / l[i]); 128c x 128i ----
__global__ __launch_bounds__(512) void k_hv(
    const short* __restrict__ whb, const short* __restrict__ xthi,
    const float* __restrict__ bhv, const float* __restrict__ lsum,
    short* __restrict__ hv2) {
  int b = blockIdx.z, c0 = blockIdx.y * 128, i0 = blockIdx.x * 128;
  int t = threadIdx.x, w = t >> 6, lane = t & 63, l15 = lane & 15, q = lane >> 4;
  int cg = w >> 2, ig = w & 3;  // 64-c half / 32-i quarter
  const short* ar = whb + (size_t)(c0 + cg * 64) * 512;
  const short* br = xthi + ((size_t)b * Nq + i0 + ig * 32) * Cq;
  f32x4 z = {0.f, 0.f, 0.f, 0.f};
  f32x4 acc[4][2];
#pragma unroll
  for (int a = 0; a < 4; a++) { acc[a][0] = z; acc[a][1] = z; }
  for (int ks = 0; ks < 16; ks++) {
    bf16x8 Bv[2];
#pragma unroll
    for (int is = 0; is < 2; is++)
      Bv[is] = *(const bf16x8*)(br + (size_t)(is * 16 + l15) * Cq + ks * 32 + q * 8);
#pragma unroll
    for (int cs = 0; cs < 4; cs++) {
      bf16x8 A = *(const bf16x8*)(ar + (size_t)(cs * 16 + l15) * 512 + ks * 32 + q * 8);
#pragma unroll
      for (int is = 0; is < 2; is++)
        acc[cs][is] = MFMA16(A, Bv[is], acc[cs][is]);
    }
  }
#pragma unroll
  for (int is = 0; is < 2; is++) {
    int i = i0 + ig * 32 + is * 16 + l15;
    float li = 1.0f / lsum[(size_t)b * Nq + i];
#pragma unroll
    for (int cs = 0; cs < 4; cs++) {
#pragma unroll
      for (int r = 0; r < 4; r++) {
        int c = c0 + cg * 64 + cs * 16 + q * 4 + r;
        float v = (acc[cs][is][r] + bhv[c]) * li;
        hv2[((size_t)b * Cq + c) * Nq + i] = f2bf(v);
      }
    }
  }
}

// ---------------- K_attn: out = gamma * hv2 @ exp(S) + x ----------------
// 256 blocks: (b, c-half 256, j-tile 128); 512 thr (8 waves).
// S phase: wave w owns j-group w (16 j), computes S for all 64 i of the tile.
// PV phase: wave w = (cw = w&3: 64-c strip, jh2 = w>>2: 64-j half).
// Double-buffered P^T tile [128 j][64 i] in LDS; 1 barrier/iter.
__global__ __launch_bounds__(512) void k_attn(
    const short* __restrict__ fhi, const short* __restrict__ flo,
    const short* __restrict__ ghi, const short* __restrict__ glo,
    const short* __restrict__ hv2, const float* __restrict__ x,
    const float* __restrict__ gp, float* __restrict__ out) {
  int L = blockIdx.x;
  int b = (L & 7) >> 1;                       // batch -> XCD pair
  int ch = L & 1;                             // c-half
  int jt = L >> 3;                            // 0..31
  int j0 = jt * 128, cbase = ch * 256;
  int t = threadIdx.x, w = t >> 6, lane = t & 63, l15 = lane & 15, q = lane >> 4;
  int cw = w & 3, jh2 = w >> 2;               // PV roles
  __shared__ short pt[2][128 * 68];           // P^T [j][i], stride 68 shorts; 34.8 KB
  float gamma = gp[0];
  f32x4 z = {0.f, 0.f, 0.f, 0.f};
  f32x4 acc[4][4];                            // [csub][jsub]
#pragma unroll
  for (int a = 0; a < 4; a++)
#pragma unroll
    for (int bb = 0; bb < 4; bb++) acc[a][bb] = z;
  // Hoist G fragments for this wave's own 16-j group (B-operand of S).
  bf16x8 GBh[2], GBl[2];
  {
    int j = j0 + w * 16 + l15;
    const short* gh = ghi + ((size_t)b * Nq + j) * 64;
    const short* gl = glo + ((size_t)b * Nq + j) * 64;
#pragma unroll
    for (int ss = 0; ss < 2; ss++) {
      GBh[ss] = *(const bf16x8*)(gh + ss * 32 + q * 8);
      GBl[ss] = *(const bf16x8*)(gl + ss * 32 + q * 8);
    }
  }
  const short* hvb = hv2 + ((size_t)b * Cq + cbase + cw * 64) * Nq;

  // S for i-tile `it`, all 4 i-subgroups (s[ig]); split hi/lo chains for ILP.
  auto computeS = [&](int it, f32x4 s[4]) {
#pragma unroll
    for (int ig = 0; ig < 4; ig++) {
      const short* fh = fhi + ((size_t)b * Nq + it * 64 + ig * 16 + l15) * 64;
      const short* fl = flo + ((size_t)b * Nq + it * 64 + ig * 16 + l15) * 64;
      f32x4 sh = z, sl = z;
#pragma unroll
      for (int ss = 0; ss < 2; ss++) {
        bf16x8 Ahi = *(const bf16x8*)(fh + ss * 32 + q * 8);
        bf16x8 Alo = *(const bf16x8*)(fl + ss * 32 + q * 8);
        sl = MFMA16(Alo, GBh[ss], sl);
        sl = MFMA16(Ahi, GBl[ss], sl);
        sh = MFMA16(Ahi, GBh[ss], sh);
      }
#pragma unroll
      for (int r = 0; r < 4; r++) s[ig][r] = sh[r] + sl[r];
    }
  };
  auto writeP = [&](int buf, f32x4 s[4]) {
    int jl = w * 16 + l15;
#pragma unroll
    for (int ig = 0; ig < 4; ig++) {
      unsigned p01 = (unsigned)(unsigned short)f2bf(__expf(s[ig][0])) |
                     ((unsigned)(unsigned short)f2bf(__expf(s[ig][1])) << 16);
      unsigned p23 = (unsigned)(unsigned short)f2bf(__expf(s[ig][2])) |
                     ((unsigned)(unsigned short)f2bf(__expf(s[ig][3])) << 16);
      uint2 pv; pv.x = p01; pv.y = p23;
      *(uint2*)(&pt[buf][jl * 68 + ig * 16 + q * 4]) = pv;   // 8B-aligned (68*j+16ig+4q)
    }
  };

  {
    f32x4 s0[4];
    computeS(0, s0);
    writeP(0, s0);
  }
  __syncthreads();
  for (int it = 0; it < 64; it++) {
    int buf = it & 1;
    int i0 = it * 64;
    f32x4 sn[4];
    if (it < 63) computeS(it + 1, sn);        // f loads overlap PV below
#pragma unroll
    for (int ss = 0; ss < 2; ss++) {
      bf16x8 PB[4];
#pragma unroll
      for (int js = 0; js < 4; js++) {
        const short* pp = &pt[buf][((jh2 * 4 + js) * 16 + l15) * 68 + ss * 32 + q * 8];
        bf16x4 a4 = *(const bf16x4*)pp;
        bf16x4 b4 = *(const bf16x4*)(pp + 4);
        PB[js] = __builtin_shufflevector(a4, b4, 0, 1, 2, 3, 4, 5, 6, 7);
      }
#pragma unroll
      for (int cs = 0; cs < 4; cs++) {
        bf16x8 A = *(const bf16x8*)(hvb + (size_t)(cs * 16 + l15) * Nq + i0 + ss * 32 + q * 8);
#pragma unroll
        for (int js = 0; js < 4; js++)
          acc[cs][js] = MFMA16(A, PB[js], acc[cs][js]);
      }
    }
    if (it < 63) writeP(1 - buf, sn);
    __syncthreads();
  }
#pragma unroll
  for (int cs = 0; cs < 4; cs++) {
#pragma unroll
    for (int js = 0; js < 4; js++) {
#pragma unroll
      for (int r = 0; r < 4; r++) {
        int c = cbase + cw * 64 + cs * 16 + q * 4 + r;
        int j = j0 + (jh2 * 4 + js) * 16 + l15;
        size_t off = ((size_t)b * Cq + c) * Nq + j;
        out[off] = gamma * acc[cs][js][r] + x[off];
      }
    }
  }
}

extern "C" void kernel_launch(void* const* d_in, const int* in_sizes, int n_in,
                              void* d_out, int out_size, void* d_ws, size_t ws_size,
                              hipStream_t stream) {
  (void)in_sizes; (void)n_in; (void)out_size; (void)ws_size;
  const float* x  = (const float*)d_in[0];
  const float* Wf = (const float*)d_in[1];
  const float* bf = (const float*)d_in[2];
  const float* Wg = (const float*)d_in[3];
  const float* bg = (const float*)d_in[4];
  const float* Wh = (const float*)d_in[5];
  const float* bh = (const float*)d_in[6];
  const float* gm = (const float*)d_in[7];
  float* out = (float*)d_out;
  char* ws = (char*)d_ws;
  // Workspace layout (bytes); total ~57 MB
  short* xthi = (short*)(ws);               // 16,777,216  (B,N,C) bf16 hi
  short* xtlo = (short*)(ws + 16777216);    // 16,777,216  lo
  short* fhi  = (short*)(ws + 33554432);    //  2,097,152  (B,N,64)
  short* flo  = (short*)(ws + 35651584);    //  2,097,152
  short* ghi  = (short*)(ws + 37748736);    //  2,097,152  (B,N,64) token-major
  short* glo  = (short*)(ws + 39845888);    //  2,097,152
  short* whi  = (short*)(ws + 41943040);    //    131,072  (128,512)
  short* wlo  = (short*)(ws + 42074112);    //    131,072
  short* whb  = (short*)(ws + 42205184);    //    524,288  (512,512)
  float* lsum = (float*)(ws + 42729472);    //     65,536  (B,N)
  short* hv2  = (short*)(ws + 42795008);    // 16,777,216  (B,C,N) bf16

  hipLaunchKernelGGL(k_prepw, dim3(1024), dim3(256), 0, stream, Wf, Wg, Wh, whi, wlo, whb);
  hipLaunchKernelGGL(k_xpose, dim3(64, 8, 4), dim3(256), 0, stream, x, xthi, xtlo);
  hipLaunchKernelGGL(k_fg, dim3(64, 4), dim3(512), 0, stream,
                     xthi, xtlo, whi, wlo, bf, bg, fhi, flo, ghi, glo);
  hipMemsetAsync(lsum, 0, 65536, stream);
  hipLaunchKernelGGL(k_stats, dim3(4, 64, 4), dim3(512), 0, stream, fhi, flo, ghi, glo, lsum);
  hipLaunchKernelGGL(k_hv, dim3(32, 4, 4), dim3(512), 0, stream, whb, xthi, bh, lsum, hv2);
  hipLaunchKernelGGL(k_attn, dim3(256), dim3(512), 0, stream,
                     fhi, flo, ghi, glo, hv2, x, gm, out);
}

// Round 4
// 701.276 us; speedup vs baseline: 1.0183x; 1.0183x over previous
//
#include <hip/hip_runtime.h>

// self_attention: B=4, C=512, C8=64, N=64*64=4096
// R4: barrier-free k_attn. Diagnosis of R1-R3: per-iter __syncthreads forces a
// full vmcnt(0) drain of ~16 scattered L2 loads with only 2 waves/SIMD resident
// -> ~80% stall regardless of tiling. New k_attn has ZERO barriers in the main
// loop: each wave owns a private 128c x 32j output tile; P round-trips through
// wave-PRIVATE LDS (lgkmcnt ordering only). j=32/wave halves the L1 line floor.
// k_stats restructured likewise: f A-frags hoisted (64 i/wave), g lines /4.

#define Bq 4
#define Cq 512
#define Nq 4096

typedef __attribute__((ext_vector_type(8))) short bf16x8;
typedef __attribute__((ext_vector_type(4))) short bf16x4;
typedef __attribute__((ext_vector_type(4))) float f32x4;

__device__ __forceinline__ short f2bf(float f) {
  unsigned u = __float_as_uint(f);
  u += 0x7fffu + ((u >> 16) & 1u);   // RNE
  return (short)(u >> 16);
}
__device__ __forceinline__ float bf2f(short h) {
  return __uint_as_float(((unsigned)(unsigned short)h) << 16);
}

#define MFMA16(A, B, C) __builtin_amdgcn_mfma_f32_16x16x32_bf16((A), (B), (C), 0, 0, 0)

// ---------------- K_prepw: W splits ----------------
__global__ __launch_bounds__(256) void k_prepw(
    const float* __restrict__ Wf, const float* __restrict__ Wg,
    const float* __restrict__ Wh,
    short* __restrict__ whi, short* __restrict__ wlo, short* __restrict__ whb) {
  int gid = blockIdx.x * 256 + threadIdx.x;  // 0..262143
  if (gid < 128 * 512) {
    int row = gid >> 9;
    float v = (row < 64) ? Wf[gid] : Wg[gid - 32768];
    short h = f2bf(v);
    whi[gid] = h;
    wlo[gid] = f2bf(v - bf2f(h));
  }
  whb[gid] = f2bf(Wh[gid]);
}

// ---------------- K_xpose: x (B,C,N) fp32 -> XT (B,N,C) bf16 hi/lo ----------------
__global__ __launch_bounds__(256) void k_xpose(
    const float* __restrict__ x, short* __restrict__ xthi, short* __restrict__ xtlo) {
  int b = blockIdx.z, c0 = blockIdx.y * 64, n0 = blockIdx.x * 64;
  __shared__ float tile[64][65];
  int t = threadIdx.x;
  int l = t & 15, g = t >> 4;
  const float* xp = x + ((size_t)b * Cq + c0) * Nq + n0;
#pragma unroll
  for (int e = 0; e < 4; e++) {
    int cl = g + e * 16;
    float4 v = *(const float4*)(xp + (size_t)cl * Nq + l * 4);
    tile[cl][l * 4 + 0] = v.x; tile[cl][l * 4 + 1] = v.y;
    tile[cl][l * 4 + 2] = v.z; tile[cl][l * 4 + 3] = v.w;
  }
  __syncthreads();
#pragma unroll
  for (int e = 0; e < 4; e++) {
    int nl = g + e * 16;
    short hi[4], lo[4];
#pragma unroll
    for (int qq = 0; qq < 4; qq++) {
      float v = tile[l * 4 + qq][nl];
      hi[qq] = f2bf(v);
      lo[qq] = f2bf(v - bf2f(hi[qq]));
    }
    size_t off = ((size_t)b * Nq + n0 + nl) * Cq + c0 + l * 4;
    *(short4*)(xthi + off) = make_short4(hi[0], hi[1], hi[2], hi[3]);
    *(short4*)(xtlo + off) = make_short4(lo[0], lo[1], lo[2], lo[3]);
  }
}

// ---------------- K_fg: f,g GEMM (split-bf16, 3 MFMAs); n-tile 64, 256 blocks ----
__global__ __launch_bounds__(512) void k_fg(
    const short* __restrict__ xthi, const short* __restrict__ xtlo,
    const short* __restrict__ whi, const short* __restrict__ wlo,
    const float* __restrict__ bfv, const float* __restrict__ bgv,
    short* __restrict__ fhi, short* __restrict__ flo,
    short* __restrict__ ghi, short* __restrict__ glo) {
  int b = blockIdx.y, n0 = blockIdx.x * 64;
  int t = threadIdx.x, w = t >> 6, lane = t & 63, l15 = lane & 15, q = lane >> 4;
  int wr = w & 3, wh = w >> 2;  // row group / o-half (0=f,1=g)
  const short* ah = xthi + ((size_t)b * Nq + n0 + wr * 16 + l15) * Cq;
  const short* al = xtlo + ((size_t)b * Nq + n0 + wr * 16 + l15) * Cq;
  f32x4 z = {0.f, 0.f, 0.f, 0.f};
  f32x4 acc[4] = {z, z, z, z};
  for (int ks = 0; ks < 16; ks++) {
    bf16x8 Ahi = *(const bf16x8*)(ah + ks * 32 + q * 8);
    bf16x8 Alo = *(const bf16x8*)(al + ks * 32 + q * 8);
#pragma unroll
    for (int os = 0; os < 4; os++) {
      int o = wh * 64 + os * 16 + l15;
      bf16x8 Bhi = *(const bf16x8*)(whi + o * 512 + ks * 32 + q * 8);
      bf16x8 Blo = *(const bf16x8*)(wlo + o * 512 + ks * 32 + q * 8);
      acc[os] = MFMA16(Alo, Bhi, acc[os]);
      acc[os] = MFMA16(Ahi, Blo, acc[os]);
      acc[os] = MFMA16(Ahi, Bhi, acc[os]);
    }
  }
#pragma unroll
  for (int os = 0; os < 4; os++) {
#pragma unroll
    for (int r = 0; r < 4; r++) {
      int og = wh * 64 + os * 16 + l15;
      int n = n0 + wr * 16 + q * 4 + r;
      float v = acc[os][r];
      if (wh == 0) {
        v += bfv[og];
        size_t off = ((size_t)b * Nq + n) * 64 + og;
        short h = f2bf(v);
        fhi[off] = h; flo[off] = f2bf(v - bf2f(h));
      } else {
        int o2 = og - 64;
        v += bgv[o2];
        size_t off = ((size_t)b * Nq + n) * 64 + o2;
        short h = f2bf(v);
        ghi[off] = h; glo[off] = f2bf(v - bf2f(h));
      }
    }
  }
}

// ---------------- K_stats: l_i += sum_j exp(S) over a 1024-j chunk ----------------
// Block: 8 waves, each wave: 64 i (A-frags hoisted, loaded once) x 128 j.
// No barriers in the j loop; reduce at end; atomicAdd into lsum (pre-zeroed).
__global__ __launch_bounds__(512) void k_stats(
    const short* __restrict__ fhi, const short* __restrict__ flo,
    const short* __restrict__ ghi, const short* __restrict__ glo,
    float* __restrict__ lsum) {
  int jc = blockIdx.x * 1024, i0 = blockIdx.y * 64, b = blockIdx.z;
  int t = threadIdx.x, w = t >> 6, lane = t & 63, l15 = lane & 15, q = lane >> 4;
  // Hoisted A-frags: 4 i-tiles x 2 k-steps x hi/lo
  bf16x8 Ahi[4][2], Alo[4][2];
#pragma unroll
  for (int ig = 0; ig < 4; ig++) {
    const short* fh = fhi + ((size_t)b * Nq + i0 + ig * 16 + l15) * 64;
    const short* fl = flo + ((size_t)b * Nq + i0 + ig * 16 + l15) * 64;
#pragma unroll
    for (int ss = 0; ss < 2; ss++) {
      Ahi[ig][ss] = *(const bf16x8*)(fh + ss * 32 + q * 8);
      Alo[ig][ss] = *(const bf16x8*)(fl + ss * 32 + q * 8);
    }
  }
  float ls[16];
#pragma unroll
  for (int a = 0; a < 16; a++) ls[a] = 0.f;
  f32x4 z = {0.f, 0.f, 0.f, 0.f};
  for (int jt = 0; jt < 8; jt++) {
    int j = jc + w * 128 + jt * 16 + l15;
    const short* gh = ghi + ((size_t)b * Nq + j) * 64;
    const short* gl = glo + ((size_t)b * Nq + j) * 64;
    bf16x8 GBh[2], GBl[2];
#pragma unroll
    for (int ss = 0; ss < 2; ss++) {
      GBh[ss] = *(const bf16x8*)(gh + ss * 32 + q * 8);
      GBl[ss] = *(const bf16x8*)(gl + ss * 32 + q * 8);
    }
#pragma unroll
    for (int ig = 0; ig < 4; ig++) {
      f32x4 sh = z, sl = z;
#pragma unroll
      for (int ss = 0; ss < 2; ss++) {
        sl = MFMA16(Alo[ig][ss], GBh[ss], sl);
        sl = MFMA16(Ahi[ig][ss], GBl[ss], sl);
        sh = MFMA16(Ahi[ig][ss], GBh[ss], sh);
      }
#pragma unroll
      for (int r = 0; r < 4; r++) ls[ig * 4 + r] += __expf(sh[r] + sl[r]);
    }
  }
  // reduce over the 16 j-lanes (l15)
#pragma unroll
  for (int m = 1; m < 16; m <<= 1) {
#pragma unroll
    for (int a = 0; a < 16; a++) ls[a] += __shfl_xor(ls[a], m, 64);
  }
  __shared__ float part[8][64];
  if (l15 == 0) {
#pragma unroll
    for (int ig = 0; ig < 4; ig++)
#pragma unroll
      for (int r = 0; r < 4; r++) part[w][ig * 16 + q * 4 + r] = ls[ig * 4 + r];
  }
  __syncthreads();
  if (t < 64) {
    float s = 0.f;
#pragma unroll
    for (int ww = 0; ww < 8; ww++) s += part[ww][t];
    atomicAdd(&lsum[(size_t)b * Nq + i0 + t], s);
  }
}

// ---------------- K_hv: hv2[b][c][i] = bf16((Wh.x + bh) / l[i]); 128c x 128i ----
__global__ __launch_bounds__(512) void k_hv(
    const short* __restrict__ whb, const short* __restrict__ xthi,
    const float* __restrict__ bhv, const float* __restrict__ lsum,
    short* __restrict__ hv2) {
  int b = blockIdx.z, c0 = blockIdx.y * 128, i0 = blockIdx.x * 128;
  int t = threadIdx.x, w = t >> 6, lane = t & 63, l15 = lane & 15, q = lane >> 4;
  int cg = w >> 2, ig = w & 3;  // 64-c half / 32-i quarter
  const short* ar = whb + (size_t)(c0 + cg * 64) * 512;
  const short* br = xthi + ((size_t)b * Nq + i0 + ig * 32) * Cq;
  f32x4 z = {0.f, 0.f, 0.f, 0.f};
  f32x4 acc[4][2];
#pragma unroll
  for (int a = 0; a < 4; a++) { acc[a][0] = z; acc[a][1] = z; }
  for (int ks = 0; ks < 16; ks++) {
    bf16x8 Bv[2];
#pragma unroll
    for (int is = 0; is < 2; is++)
      Bv[is] = *(const bf16x8*)(br + (size_t)(is * 16 + l15) * Cq + ks * 32 + q * 8);
#pragma unroll
    for (int cs = 0; cs < 4; cs++) {
      bf16x8 A = *(const bf16x8*)(ar + (size_t)(cs * 16 + l15) * 512 + ks * 32 + q * 8);
#pragma unroll
      for (int is = 0; is < 2; is++)
        acc[cs][is] = MFMA16(A, Bv[is], acc[cs][is]);
    }
  }
#pragma unroll
  for (int is = 0; is < 2; is++) {
    int i = i0 + ig * 32 + is * 16 + l15;
    float li = 1.0f / lsum[(size_t)b * Nq + i];
#pragma unroll
    for (int cs = 0; cs < 4; cs++) {
#pragma unroll
      for (int r = 0; r < 4; r++) {
        int c = c0 + cg * 64 + cs * 16 + q * 4 + r;
        float v = (acc[cs][is][r] + bhv[c]) * li;
        hv2[((size_t)b * Cq + c) * Nq + i] = f2bf(v);
      }
    }
  }
}

// ---------------- K_attn: out = gamma * hv2 @ exp(S) + x  (BARRIER-FREE) ---------
// 512 blocks x 256 thr (4 waves). Wave owns 128c x 32j output tile.
// Per 64-i chunk: S (48 MFMA, split-bf16) -> exp -> wave-PRIVATE LDS P tile
// (double-buffered, lgkmcnt ordering only, NO __syncthreads) -> PV (32 MFMA).
__global__ __launch_bounds__(256, 2) void k_attn(
    const short* __restrict__ fhi, const short* __restrict__ flo,
    const short* __restrict__ ghi, const short* __restrict__ glo,
    const short* __restrict__ hv2, const float* __restrict__ x,
    const float* __restrict__ gp, float* __restrict__ out) {
  int L = blockIdx.x;
  int xgrp = L & 7;                       // XCD group: (b, ch-pair) locality
  int sub = (L >> 3) & 1;
  int jb = L >> 4;                        // 0..31
  int b = xgrp >> 1;
  int chq = (xgrp & 1) * 2 + sub;         // c-quarter 0..3
  int c0 = chq * 128;
  int t = threadIdx.x, w = t >> 6, lane = t & 63, l15 = lane & 15, q = lane >> 4;
  int j0w = jb * 128 + w * 32;            // wave's 32-j strip
  // wave-private P tile: [32 j][80 shorts] x 2 buffers (stride 160 B, 16B-aligned)
  __shared__ short pt[4][2][32 * 80];
  float gamma = gp[0];
  f32x4 z = {0.f, 0.f, 0.f, 0.f};
  f32x4 acc[8][2];                        // [c-tile][j-tile]
#pragma unroll
  for (int a = 0; a < 8; a++) { acc[a][0] = z; acc[a][1] = z; }
  // G frags for this wave's 2 j-tiles (resident).
  bf16x8 GBh[2][2], GBl[2][2];            // [jt][ss]
#pragma unroll
  for (int jt = 0; jt < 2; jt++) {
    int j = j0w + jt * 16 + l15;
    const short* gh = ghi + ((size_t)b * Nq + j) * 64;
    const short* gl = glo + ((size_t)b * Nq + j) * 64;
#pragma unroll
    for (int ss = 0; ss < 2; ss++) {
      GBh[jt][ss] = *(const bf16x8*)(gh + ss * 32 + q * 8);
      GBl[jt][ss] = *(const bf16x8*)(gl + ss * 32 + q * 8);
    }
  }
  const short* hvb = hv2 + ((size_t)b * Cq + c0) * Nq;
  const size_t fbase = (size_t)b * Nq;

  for (int it = 0; it < 64; it++) {
    short* ptw = &pt[w][it & 1][0];
    // ---- S phase: 64 i x 32 j, split-bf16 ----
#pragma unroll
    for (int ig = 0; ig < 4; ig++) {
      const short* fh = fhi + (fbase + it * 64 + ig * 16 + l15) * 64;
      const short* fl = flo + (fbase + it * 64 + ig * 16 + l15) * 64;
      bf16x8 Ah[2], Al[2];
#pragma unroll
      for (int ss = 0; ss < 2; ss++) {
        Ah[ss] = *(const bf16x8*)(fh + ss * 32 + q * 8);
        Al[ss] = *(const bf16x8*)(fl + ss * 32 + q * 8);
      }
#pragma unroll
      for (int jt = 0; jt < 2; jt++) {
        f32x4 sh = z, sl = z;
#pragma unroll
        for (int ss = 0; ss < 2; ss++) {
          sl = MFMA16(Al[ss], GBh[jt][ss], sl);
          sl = MFMA16(Ah[ss], GBl[jt][ss], sl);
          sh = MFMA16(Ah[ss], GBh[jt][ss], sh);
        }
        unsigned p01 = (unsigned)(unsigned short)f2bf(__expf(sh[0] + sl[0])) |
                       ((unsigned)(unsigned short)f2bf(__expf(sh[1] + sl[1])) << 16);
        unsigned p23 = (unsigned)(unsigned short)f2bf(__expf(sh[2] + sl[2])) |
                       ((unsigned)(unsigned short)f2bf(__expf(sh[3] + sl[3])) << 16);
        int idx = (jt * 16 + l15) * 80 + ig * 16 + q * 4;
        *(unsigned*)(ptw + idx) = p01;
        *(unsigned*)(ptw + idx + 2) = p23;
      }
    }
    // ---- PV phase: read own P (lgkmcnt ordering), 2 K-chunks x 8 c-tiles ----
#pragma unroll
    for (int ic = 0; ic < 2; ic++) {
      bf16x8 PB[2];
#pragma unroll
      for (int jt = 0; jt < 2; jt++)
        PB[jt] = *(const bf16x8*)(ptw + (jt * 16 + l15) * 80 + ic * 32 + q * 8);
      const short* hp = hvb + it * 64 + ic * 32 + q * 8;
#pragma unroll
      for (int ct = 0; ct < 8; ct++) {
        bf16x8 A = *(const bf16x8*)(hp + (size_t)(ct * 16 + l15) * Nq);
#pragma unroll
        for (int jt = 0; jt < 2; jt++)
          acc[ct][jt] = MFMA16(A, PB[jt], acc[ct][jt]);
      }
    }
  }
  // ---- epilogue ----
#pragma unroll
  for (int ct = 0; ct < 8; ct++) {
#pragma unroll
    for (int jt = 0; jt < 2; jt++) {
#pragma unroll
      for (int r = 0; r < 4; r++) {
        int c = c0 + ct * 16 + q * 4 + r;
        int j = j0w + jt * 16 + l15;
        size_t off = ((size_t)b * Cq + c) * Nq + j;
        out[off] = gamma * acc[ct][jt][r] + x[off];
      }
    }
  }
}

extern "C" void kernel_launch(void* const* d_in, const int* in_sizes, int n_in,
                              void* d_out, int out_size, void* d_ws, size_t ws_size,
                              hipStream_t stream) {
  (void)in_sizes; (void)n_in; (void)out_size; (void)ws_size;
  const float* x  = (const float*)d_in[0];
  const float* Wf = (const float*)d_in[1];
  const float* bf = (const float*)d_in[2];
  const float* Wg = (const float*)d_in[3];
  const float* bg = (const float*)d_in[4];
  const float* Wh = (const float*)d_in[5];
  const float* bh = (const float*)d_in[6];
  const float* gm = (const float*)d_in[7];
  float* out = (float*)d_out;
  char* ws = (char*)d_ws;
  // Workspace layout (bytes); total ~57 MB
  short* xthi = (short*)(ws);               // 16,777,216  (B,N,C) bf16 hi
  short* xtlo = (short*)(ws + 16777216);    // 16,777,216  lo
  short* fhi  = (short*)(ws + 33554432);    //  2,097,152  (B,N,64)
  short* flo  = (short*)(ws + 35651584);    //  2,097,152
  short* ghi  = (short*)(ws + 37748736);    //  2,097,152  (B,N,64) token-major
  short* glo  = (short*)(ws + 39845888);    //  2,097,152
  short* whi  = (short*)(ws + 41943040);    //    131,072  (128,512)
  short* wlo  = (short*)(ws + 42074112);    //    131,072
  short* whb  = (short*)(ws + 42205184);    //    524,288  (512,512)
  float* lsum = (float*)(ws + 42729472);    //     65,536  (B,N)
  short* hv2  = (short*)(ws + 42795008);    // 16,777,216  (B,C,N) bf16

  hipLaunchKernelGGL(k_prepw, dim3(1024), dim3(256), 0, stream, Wf, Wg, Wh, whi, wlo, whb);
  hipLaunchKernelGGL(k_xpose, dim3(64, 8, 4), dim3(256), 0, stream, x, xthi, xtlo);
  hipLaunchKernelGGL(k_fg, dim3(64, 4), dim3(512), 0, stream,
                     xthi, xtlo, whi, wlo, bf, bg, fhi, flo, ghi, glo);
  hipMemsetAsync(lsum, 0, 65536, stream);
  hipLaunchKernelGGL(k_stats, dim3(4, 64, 4), dim3(512), 0, stream, fhi, flo, ghi, glo, lsum);
  hipLaunchKernelGGL(k_hv, dim3(32, 4, 4), dim3(512), 0, stream, whb, xthi, bh, lsum, hv2);
  hipLaunchKernelGGL(k_attn, dim3(512), dim3(256), 0, stream,
                     fhi, flo, ghi, glo, hv2, x, gm, out);
}

// Round 5
// 349.904 us; speedup vs baseline: 2.0409x; 2.0042x over previous
//
#include <hip/hip_runtime.h>

// self_attention: B=4, C=512, C8=64, N=64*64=4096
// R5: fragment-packed global layouts. R1-R4 post-mortems: every MFMA operand
// load was a 16-row gather (lane=row, rows 8KB apart) -> TA segment-bound.
// Now f/g/hv are stored pre-swizzled in MFMA fragment order: one fragment =
// 64 lanes x 16 B = 1024 contiguous bytes -> single-segment loads.
//   ffrag/gfrag[b][t16][ss][lane][8]  (A/B frags of the 64-wide f/g)
//   hvfrag[b][tc(32)][si(128)][lane][8]  (PV A-operand, hv/l in bf16)
// k_attn: 256 blocks (b x c-half x j128), 8 waves (4cg x 2jg), wave 64c x 64j,
// P^T via LDS (stride 88, dbuf, 1 barrier/iter). All other loads coalesced.

#define Bq 4
#define Cq 512
#define Nq 4096
#define PSTR 88

typedef __attribute__((ext_vector_type(8))) short bf16x8;
typedef __attribute__((ext_vector_type(4))) float f32x4;

__device__ __forceinline__ short f2bf(float f) {
  unsigned u = __float_as_uint(f);
  u += 0x7fffu + ((u >> 16) & 1u);   // RNE
  return (short)(u >> 16);
}
__device__ __forceinline__ float bf2f(short h) {
  return __uint_as_float(((unsigned)(unsigned short)h) << 16);
}

#define MFMA16(A, B, C) __builtin_amdgcn_mfma_f32_16x16x32_bf16((A), (B), (C), 0, 0, 0)

// frag base (in shorts) for f/g token-tile t16 (16 tokens), k-chunk ss (32 of 64)
__device__ __forceinline__ size_t fg_frag(int b, int t16, int ss) {
  return ((size_t)((b * 256 + t16) * 2 + ss)) * 512;
}
// frag base for hv c-tile tc (16 c), i-chunk si (32 of 4096)
__device__ __forceinline__ size_t hv_frag(int b, int tc, int si) {
  return ((size_t)((b * 32 + tc) * 128 + si)) * 512;
}

// ---------------- K_prepw: W splits ----------------
__global__ __launch_bounds__(256) void k_prepw(
    const float* __restrict__ Wf, const float* __restrict__ Wg,
    const float* __restrict__ Wh,
    short* __restrict__ whi, short* __restrict__ wlo, short* __restrict__ whb) {
  int gid = blockIdx.x * 256 + threadIdx.x;  // 0..262143
  if (gid < 128 * 512) {
    int row = gid >> 9;
    float v = (row < 64) ? Wf[gid] : Wg[gid - 32768];
    short h = f2bf(v);
    whi[gid] = h;
    wlo[gid] = f2bf(v - bf2f(h));
  }
  whb[gid] = f2bf(Wh[gid]);
}

// ---------------- K_xpose: x (B,C,N) fp32 -> XT (B,N,C) bf16 hi/lo ----------------
__global__ __launch_bounds__(256) void k_xpose(
    const float* __restrict__ x, short* __restrict__ xthi, short* __restrict__ xtlo) {
  int b = blockIdx.z, c0 = blockIdx.y * 64, n0 = blockIdx.x * 64;
  __shared__ float tile[64][65];
  int t = threadIdx.x;
  int l = t & 15, g = t >> 4;
  const float* xp = x + ((size_t)b * Cq + c0) * Nq + n0;
#pragma unroll
  for (int e = 0; e < 4; e++) {
    int cl = g + e * 16;
    float4 v = *(const float4*)(xp + (size_t)cl * Nq + l * 4);
    tile[cl][l * 4 + 0] = v.x; tile[cl][l * 4 + 1] = v.y;
    tile[cl][l * 4 + 2] = v.z; tile[cl][l * 4 + 3] = v.w;
  }
  __syncthreads();
#pragma unroll
  for (int e = 0; e < 4; e++) {
    int nl = g + e * 16;
    short hi[4], lo[4];
#pragma unroll
    for (int qq = 0; qq < 4; qq++) {
      float v = tile[l * 4 + qq][nl];
      hi[qq] = f2bf(v);
      lo[qq] = f2bf(v - bf2f(hi[qq]));
    }
    size_t off = ((size_t)b * Nq + n0 + nl) * Cq + c0 + l * 4;
    *(short4*)(xthi + off) = make_short4(hi[0], hi[1], hi[2], hi[3]);
    *(short4*)(xtlo + off) = make_short4(lo[0], lo[1], lo[2], lo[3]);
  }
}

// ---------------- K_fg: f,g GEMM -> frag-packed stores ----------------
__global__ __launch_bounds__(512) void k_fg(
    const short* __restrict__ xthi, const short* __restrict__ xtlo,
    const short* __restrict__ whi, const short* __restrict__ wlo,
    const float* __restrict__ bfv, const float* __restrict__ bgv,
    short* __restrict__ ffh, short* __restrict__ ffl,
    short* __restrict__ gfh, short* __restrict__ gfl) {
  int b = blockIdx.y, n0 = blockIdx.x * 64;
  int t = threadIdx.x, w = t >> 6, lane = t & 63, l15 = lane & 15, q = lane >> 4;
  int wr = w & 3, wh = w >> 2;  // row group / o-half (0=f,1=g)
  const short* ah = xthi + ((size_t)b * Nq + n0 + wr * 16 + l15) * Cq;
  const short* al = xtlo + ((size_t)b * Nq + n0 + wr * 16 + l15) * Cq;
  f32x4 z = {0.f, 0.f, 0.f, 0.f};
  f32x4 acc[4] = {z, z, z, z};
  for (int ks = 0; ks < 16; ks++) {
    bf16x8 Ahi = *(const bf16x8*)(ah + ks * 32 + q * 8);
    bf16x8 Alo = *(const bf16x8*)(al + ks * 32 + q * 8);
#pragma unroll
    for (int os = 0; os < 4; os++) {
      int o = wh * 64 + os * 16 + l15;
      bf16x8 Bhi = *(const bf16x8*)(whi + o * 512 + ks * 32 + q * 8);
      bf16x8 Blo = *(const bf16x8*)(wlo + o * 512 + ks * 32 + q * 8);
      acc[os] = MFMA16(Alo, Bhi, acc[os]);
      acc[os] = MFMA16(Ahi, Blo, acc[os]);
      acc[os] = MFMA16(Ahi, Bhi, acc[os]);
    }
  }
#pragma unroll
  for (int os = 0; os < 4; os++) {
#pragma unroll
    for (int r = 0; r < 4; r++) {
      int o = os * 16 + l15;                 // 0..63 within f or g
      int n = n0 + wr * 16 + q * 4 + r;
      float v = acc[os][r] + (wh == 0 ? bfv[o] : bgv[o]);
      size_t off = ((size_t)((b * 256 + (n >> 4)) * 2 + (o >> 5))) * 512
                 + (((o >> 3) & 3) * 16 + (n & 15)) * 8 + (o & 7);
      short h = f2bf(v);
      short lo = f2bf(v - bf2f(h));
      if (wh == 0) { ffh[off] = h; ffl[off] = lo; }
      else         { gfh[off] = h; gfl[off] = lo; }
    }
  }
}

// ---------------- K_stats: partial l_i = sum_j exp(S) over a 1024-j chunk ----
// Frag-packed coalesced loads; wave owns 64i x 128j; no inner barriers.
__global__ __launch_bounds__(512) void k_stats(
    const short* __restrict__ ffh, const short* __restrict__ ffl,
    const short* __restrict__ gfh, const short* __restrict__ gfl,
    float* __restrict__ lsum) {
  int jc = blockIdx.x * 1024, i0 = blockIdx.y * 64, b = blockIdx.z;
  int t = threadIdx.x, w = t >> 6, lane = t & 63, l15 = lane & 15, q = lane >> 4;
  bf16x8 Ahi[4][2], Alo[4][2];
#pragma unroll
  for (int ig = 0; ig < 4; ig++)
#pragma unroll
    for (int ss = 0; ss < 2; ss++) {
      size_t base = fg_frag(b, (i0 >> 4) + ig, ss) + lane * 8;
      Ahi[ig][ss] = *(const bf16x8*)(ffh + base);
      Alo[ig][ss] = *(const bf16x8*)(ffl + base);
    }
  float ls[16];
#pragma unroll
  for (int a = 0; a < 16; a++) ls[a] = 0.f;
  f32x4 z = {0.f, 0.f, 0.f, 0.f};
  for (int jt = 0; jt < 8; jt++) {
    int tj = (jc >> 4) + w * 8 + jt;
    bf16x8 GBh[2], GBl[2];
#pragma unroll
    for (int ss = 0; ss < 2; ss++) {
      size_t base = fg_frag(b, tj, ss) + lane * 8;
      GBh[ss] = *(const bf16x8*)(gfh + base);
      GBl[ss] = *(const bf16x8*)(gfl + base);
    }
#pragma unroll
    for (int ig = 0; ig < 4; ig++) {
      f32x4 sh = z, sl = z;
#pragma unroll
      for (int ss = 0; ss < 2; ss++) {
        sl = MFMA16(Alo[ig][ss], GBh[ss], sl);
        sl = MFMA16(Ahi[ig][ss], GBl[ss], sl);
        sh = MFMA16(Ahi[ig][ss], GBh[ss], sh);
      }
#pragma unroll
      for (int r = 0; r < 4; r++) ls[ig * 4 + r] += __expf(sh[r] + sl[r]);
    }
  }
#pragma unroll
  for (int m = 1; m < 16; m <<= 1) {
#pragma unroll
    for (int a = 0; a < 16; a++) ls[a] += __shfl_xor(ls[a], m, 64);
  }
  __shared__ float part[8][64];
  if (l15 == 0) {
#pragma unroll
    for (int ig = 0; ig < 4; ig++)
#pragma unroll
      for (int r = 0; r < 4; r++) part[w][ig * 16 + q * 4 + r] = ls[ig * 4 + r];
  }
  __syncthreads();
  if (t < 64) {
    float s = 0.f;
#pragma unroll
    for (int ww = 0; ww < 8; ww++) s += part[ww][t];
    atomicAdd(&lsum[(size_t)b * Nq + i0 + t], s);
  }
}

// ---------------- K_hv: hvfrag = frag-packed bf16((Wh.x + bh)/l) ----------------
// Swapped operands: D[m=i][n=c] so C-frag is i-contiguous per lane; in-wave
// shuffle repack to A-frag order; coalesced 16-B stores. Grid (128 si, 4 b).
__global__ __launch_bounds__(512) void k_hv(
    const short* __restrict__ whb, const short* __restrict__ xthi,
    const float* __restrict__ bhv, const float* __restrict__ lsum,
    short* __restrict__ hvf) {
  int si = blockIdx.x, b = blockIdx.y;
  int t = threadIdx.x, w = t >> 6, lane = t & 63, l15 = lane & 15, q = lane >> 4;
  int c0 = w * 64;
  const short* ar0 = xthi + ((size_t)b * Nq + si * 32 + l15) * Cq;
  const short* ar1 = ar0 + 16 * Cq;
  f32x4 z = {0.f, 0.f, 0.f, 0.f};
  f32x4 acc[2][4];
#pragma unroll
  for (int a = 0; a < 2; a++)
#pragma unroll
    for (int c = 0; c < 4; c++) acc[a][c] = z;
  for (int ks = 0; ks < 16; ks++) {
    bf16x8 A0 = *(const bf16x8*)(ar0 + ks * 32 + q * 8);
    bf16x8 A1 = *(const bf16x8*)(ar1 + ks * 32 + q * 8);
#pragma unroll
    for (int ct = 0; ct < 4; ct++) {
      bf16x8 Bv = *(const bf16x8*)(whb + (size_t)(c0 + ct * 16 + l15) * 512 + ks * 32 + q * 8);
      acc[0][ct] = MFMA16(A0, Bv, acc[0][ct]);
      acc[1][ct] = MFMA16(A1, Bv, acc[1][ct]);
    }
  }
  // per-lane i rows: i = si*32 + it*16 + q*4 + r
  float li[2][4];
#pragma unroll
  for (int it = 0; it < 2; it++)
#pragma unroll
    for (int r = 0; r < 4; r++)
      li[it][r] = 1.0f / lsum[(size_t)b * Nq + si * 32 + it * 16 + q * 4 + r];
  int src0 = ((q & 1) << 5) + l15;
  int src1 = src0 + 16;
  int hiSel = q >> 1;
#pragma unroll
  for (int ct = 0; ct < 4; ct++) {
    float bias = bhv[c0 + ct * 16 + l15];
    unsigned u01[2], u23[2];
#pragma unroll
    for (int it = 0; it < 2; it++) {
      float v0 = (acc[it][ct][0] + bias) * li[it][0];
      float v1 = (acc[it][ct][1] + bias) * li[it][1];
      float v2 = (acc[it][ct][2] + bias) * li[it][2];
      float v3 = (acc[it][ct][3] + bias) * li[it][3];
      u01[it] = (unsigned)(unsigned short)f2bf(v0) | ((unsigned)(unsigned short)f2bf(v1) << 16);
      u23[it] = (unsigned)(unsigned short)f2bf(v2) | ((unsigned)(unsigned short)f2bf(v3) << 16);
    }
    unsigned a0 = __shfl((int)u01[0], src0), b0 = __shfl((int)u01[1], src0);
    unsigned a1 = __shfl((int)u23[0], src0), b1 = __shfl((int)u23[1], src0);
    unsigned a2 = __shfl((int)u01[0], src1), b2 = __shfl((int)u01[1], src1);
    unsigned a3 = __shfl((int)u23[0], src1), b3 = __shfl((int)u23[1], src1);
    uint4 st;
    st.x = hiSel ? b0 : a0;
    st.y = hiSel ? b1 : a1;
    st.z = hiSel ? b2 : a2;
    st.w = hiSel ? b3 : a3;
    *(uint4*)(hvf + hv_frag(b, (c0 >> 4) + ct, si) + (size_t)lane * 8) = st;
  }
}

// ---------------- K_attn: out = gamma * hv2 @ exp(S) + x ----------------
// 256 blocks (b x c-half 256 x j-tile 128), 512 thr = 4cg x 2jg waves.
// Wave tile 64c x 64j. All global loads = single-segment 1024-B frag loads.
// P^T in LDS (stride 88), double-buffered, 1 barrier/iter.
__global__ __launch_bounds__(512, 2) void k_attn(
    const short* __restrict__ ffh, const short* __restrict__ ffl,
    const short* __restrict__ gfh, const short* __restrict__ gfl,
    const short* __restrict__ hvf, const float* __restrict__ x,
    const float* __restrict__ gp, float* __restrict__ out) {
  int L = blockIdx.x;
  int b = (L & 7) >> 1;                   // batch -> XCD pair
  int ch = L & 1;                         // c-half
  int jt32 = L >> 3;                      // 0..31
  int j0 = jt32 * 128, c0 = ch * 256;
  int t = threadIdx.x, w = t >> 6, lane = t & 63, l15 = lane & 15, q = lane >> 4;
  int cg = w & 3, jg = w >> 2;
  __shared__ __align__(16) short pt[2][128 * PSTR];
  float gamma = gp[0];
  f32x4 z = {0.f, 0.f, 0.f, 0.f};
  f32x4 acc[4][4];                        // [ct][jt]
#pragma unroll
  for (int a = 0; a < 4; a++)
#pragma unroll
    for (int bb = 0; bb < 4; bb++) acc[a][bb] = z;
  // Hoist g frags for this wave's 64 j (coalesced, once).
  bf16x8 GBh[4][2], GBl[4][2];
#pragma unroll
  for (int jt = 0; jt < 4; jt++)
#pragma unroll
    for (int ss = 0; ss < 2; ss++) {
      size_t base = fg_frag(b, (j0 >> 4) + jg * 4 + jt, ss) + lane * 8;
      GBh[jt][ss] = *(const bf16x8*)(gfh + base);
      GBl[jt][ss] = *(const bf16x8*)(gfl + base);
    }

  auto computeS = [&](int it, int buf) {
    bf16x8 Ah[2], Al[2];
#pragma unroll
    for (int ss = 0; ss < 2; ss++) {
      size_t base = fg_frag(b, it * 4 + cg, ss) + lane * 8;
      Ah[ss] = *(const bf16x8*)(ffh + base);
      Al[ss] = *(const bf16x8*)(ffl + base);
    }
#pragma unroll
    for (int jt = 0; jt < 4; jt++) {
      f32x4 sh = z, sl = z;
#pragma unroll
      for (int ss = 0; ss < 2; ss++) {
        sl = MFMA16(Al[ss], GBh[jt][ss], sl);
        sl = MFMA16(Ah[ss], GBl[jt][ss], sl);
        sh = MFMA16(Ah[ss], GBh[jt][ss], sh);
      }
      unsigned p01 = (unsigned)(unsigned short)f2bf(__expf(sh[0] + sl[0])) |
                     ((unsigned)(unsigned short)f2bf(__expf(sh[1] + sl[1])) << 16);
      unsigned p23 = (unsigned)(unsigned short)f2bf(__expf(sh[2] + sl[2])) |
                     ((unsigned)(unsigned short)f2bf(__expf(sh[3] + sl[3])) << 16);
      uint2 pv; pv.x = p01; pv.y = p23;
      *(uint2*)(&pt[buf][(jg * 64 + jt * 16 + l15) * PSTR + cg * 16 + q * 4]) = pv;
    }
  };

  computeS(0, 0);
  for (int it = 0; it < 64; it++) {
    __syncthreads();
    int buf = it & 1;
    if (it < 63) computeS(it + 1, 1 - buf);
#pragma unroll
    for (int ss = 0; ss < 2; ss++) {
      bf16x8 PB[4];
#pragma unroll
      for (int jt = 0; jt < 4; jt++)
        PB[jt] = *(const bf16x8*)(&pt[buf][(jg * 64 + jt * 16 + l15) * PSTR + ss * 32 + q * 8]);
#pragma unroll
      for (int ct = 0; ct < 4; ct++) {
        size_t hb = hv_frag(b, (c0 >> 4) + cg * 4 + ct, it * 2 + ss) + lane * 8;
        bf16x8 A = *(const bf16x8*)(hvf + hb);
#pragma unroll
        for (int jt = 0; jt < 4; jt++)
          acc[ct][jt] = MFMA16(A, PB[jt], acc[ct][jt]);
      }
    }
  }
  // epilogue: D rows = c (q*4+r within ct tile), cols = j (l15)
#pragma unroll
  for (int ct = 0; ct < 4; ct++) {
#pragma unroll
    for (int jt = 0; jt < 4; jt++) {
#pragma unroll
      for (int r = 0; r < 4; r++) {
        int c = c0 + cg * 64 + ct * 16 + q * 4 + r;
        int j = j0 + jg * 64 + jt * 16 + l15;
        size_t off = ((size_t)b * Cq + c) * Nq + j;
        out[off] = gamma * acc[ct][jt][r] + x[off];
      }
    }
  }
}

extern "C" void kernel_launch(void* const* d_in, const int* in_sizes, int n_in,
                              void* d_out, int out_size, void* d_ws, size_t ws_size,
                              hipStream_t stream) {
  (void)in_sizes; (void)n_in; (void)out_size; (void)ws_size;
  const float* x  = (const float*)d_in[0];
  const float* Wf = (const float*)d_in[1];
  const float* bf = (const float*)d_in[2];
  const float* Wg = (const float*)d_in[3];
  const float* bg = (const float*)d_in[4];
  const float* Wh = (const float*)d_in[5];
  const float* bh = (const float*)d_in[6];
  const float* gm = (const float*)d_in[7];
  float* out = (float*)d_out;
  char* ws = (char*)d_ws;
  // Workspace layout (bytes); total 59,572,224 (~57 MB)
  short* xthi = (short*)(ws);               // 16,777,216  (B,N,C) bf16 hi
  short* xtlo = (short*)(ws + 16777216);    // 16,777,216  lo
  short* ffh  = (short*)(ws + 33554432);    //  2,097,152  f frag-packed hi
  short* ffl  = (short*)(ws + 35651584);    //  2,097,152  f lo
  short* gfh  = (short*)(ws + 37748736);    //  2,097,152  g frag-packed hi
  short* gfl  = (short*)(ws + 39845888);    //  2,097,152  g lo
  short* whi  = (short*)(ws + 41943040);    //    131,072  (128,512)
  short* wlo  = (short*)(ws + 42074112);    //    131,072
  short* whb  = (short*)(ws + 42205184);    //    524,288  (512,512)
  float* lsum = (float*)(ws + 42729472);    //     65,536  (B,N)
  short* hvf  = (short*)(ws + 42795008);    // 16,777,216  hv frag-packed bf16

  hipLaunchKernelGGL(k_prepw, dim3(1024), dim3(256), 0, stream, Wf, Wg, Wh, whi, wlo, whb);
  hipLaunchKernelGGL(k_xpose, dim3(64, 8, 4), dim3(256), 0, stream, x, xthi, xtlo);
  hipLaunchKernelGGL(k_fg, dim3(64, 4), dim3(512), 0, stream,
                     xthi, xtlo, whi, wlo, bf, bg, ffh, ffl, gfh, gfl);
  hipMemsetAsync(lsum, 0, 65536, stream);
  hipLaunchKernelGGL(k_stats, dim3(4, 64, 4), dim3(512), 0, stream, ffh, ffl, gfh, gfl, lsum);
  hipLaunchKernelGGL(k_hv, dim3(128, 4), dim3(512), 0, stream, whb, xthi, bh, lsum, hvf);
  hipLaunchKernelGGL(k_attn, dim3(256), dim3(512), 0, stream,
                     ffh, ffl, gfh, gfl, hvf, x, gm, out);
}

// Round 6
// 338.227 us; speedup vs baseline: 2.1114x; 1.0345x over previous
//
#include <hip/hip_runtime.h>

// self_attention: B=4, C=512, C8=64, N=64*64=4096
// R6: (a) k_attn covers ALL 512 c per block (b x j64 -> 256 blocks): S-tile no
// longer duplicated across c-halves -> 44 MFMA/wave-iter (was 56). Same
// frag-packed coalesced loads (the R5 win), same 1-barrier dbuf P^T LDS.
// (b) k_stats writes 4 disjoint partial buffers (no atomics, no memset
// dispatch); k_hv sums them.

#define Bq 4
#define Cq 512
#define Nq 4096
#define PSTR 72   // P^T row stride in shorts (144 B = 9*16 -> b128-aligned rows)

typedef __attribute__((ext_vector_type(8))) short bf16x8;
typedef __attribute__((ext_vector_type(4))) float f32x4;

__device__ __forceinline__ short f2bf(float f) {
  unsigned u = __float_as_uint(f);
  u += 0x7fffu + ((u >> 16) & 1u);   // RNE
  return (short)(u >> 16);
}
__device__ __forceinline__ float bf2f(short h) {
  return __uint_as_float(((unsigned)(unsigned short)h) << 16);
}

#define MFMA16(A, B, C) __builtin_amdgcn_mfma_f32_16x16x32_bf16((A), (B), (C), 0, 0, 0)

// frag base (in shorts) for f/g token-tile t16 (16 tokens), k-chunk ss (32 of 64)
__device__ __forceinline__ size_t fg_frag(int b, int t16, int ss) {
  return ((size_t)((b * 256 + t16) * 2 + ss)) * 512;
}
// frag base for hv c-tile tc (16 c), i-chunk si (32 of 4096)
__device__ __forceinline__ size_t hv_frag(int b, int tc, int si) {
  return ((size_t)((b * 32 + tc) * 128 + si)) * 512;
}

// ---------------- K_prepw: W splits ----------------
__global__ __launch_bounds__(256) void k_prepw(
    const float* __restrict__ Wf, const float* __restrict__ Wg,
    const float* __restrict__ Wh,
    short* __restrict__ whi, short* __restrict__ wlo, short* __restrict__ whb) {
  int gid = blockIdx.x * 256 + threadIdx.x;  // 0..262143
  if (gid < 128 * 512) {
    int row = gid >> 9;
    float v = (row < 64) ? Wf[gid] : Wg[gid - 32768];
    short h = f2bf(v);
    whi[gid] = h;
    wlo[gid] = f2bf(v - bf2f(h));
  }
  whb[gid] = f2bf(Wh[gid]);
}

// ---------------- K_xpose: x (B,C,N) fp32 -> XT (B,N,C) bf16 hi/lo ----------------
__global__ __launch_bounds__(256) void k_xpose(
    const float* __restrict__ x, short* __restrict__ xthi, short* __restrict__ xtlo) {
  int b = blockIdx.z, c0 = blockIdx.y * 64, n0 = blockIdx.x * 64;
  __shared__ float tile[64][65];
  int t = threadIdx.x;
  int l = t & 15, g = t >> 4;
  const float* xp = x + ((size_t)b * Cq + c0) * Nq + n0;
#pragma unroll
  for (int e = 0; e < 4; e++) {
    int cl = g + e * 16;
    float4 v = *(const float4*)(xp + (size_t)cl * Nq + l * 4);
    tile[cl][l * 4 + 0] = v.x; tile[cl][l * 4 + 1] = v.y;
    tile[cl][l * 4 + 2] = v.z; tile[cl][l * 4 + 3] = v.w;
  }
  __syncthreads();
#pragma unroll
  for (int e = 0; e < 4; e++) {
    int nl = g + e * 16;
    short hi[4], lo[4];
#pragma unroll
    for (int qq = 0; qq < 4; qq++) {
      float v = tile[l * 4 + qq][nl];
      hi[qq] = f2bf(v);
      lo[qq] = f2bf(v - bf2f(hi[qq]));
    }
    size_t off = ((size_t)b * Nq + n0 + nl) * Cq + c0 + l * 4;
    *(short4*)(xthi + off) = make_short4(hi[0], hi[1], hi[2], hi[3]);
    *(short4*)(xtlo + off) = make_short4(lo[0], lo[1], lo[2], lo[3]);
  }
}

// ---------------- K_fg: f,g GEMM -> frag-packed stores ----------------
__global__ __launch_bounds__(512) void k_fg(
    const short* __restrict__ xthi, const short* __restrict__ xtlo,
    const short* __restrict__ whi, const short* __restrict__ wlo,
    const float* __restrict__ bfv, const float* __restrict__ bgv,
    short* __restrict__ ffh, short* __restrict__ ffl,
    short* __restrict__ gfh, short* __restrict__ gfl) {
  int b = blockIdx.y, n0 = blockIdx.x * 64;
  int t = threadIdx.x, w = t >> 6, lane = t & 63, l15 = lane & 15, q = lane >> 4;
  int wr = w & 3, wh = w >> 2;  // row group / o-half (0=f,1=g)
  const short* ah = xthi + ((size_t)b * Nq + n0 + wr * 16 + l15) * Cq;
  const short* al = xtlo + ((size_t)b * Nq + n0 + wr * 16 + l15) * Cq;
  f32x4 z = {0.f, 0.f, 0.f, 0.f};
  f32x4 acc[4] = {z, z, z, z};
  for (int ks = 0; ks < 16; ks++) {
    bf16x8 Ahi = *(const bf16x8*)(ah + ks * 32 + q * 8);
    bf16x8 Alo = *(const bf16x8*)(al + ks * 32 + q * 8);
#pragma unroll
    for (int os = 0; os < 4; os++) {
      int o = wh * 64 + os * 16 + l15;
      bf16x8 Bhi = *(const bf16x8*)(whi + o * 512 + ks * 32 + q * 8);
      bf16x8 Blo = *(const bf16x8*)(wlo + o * 512 + ks * 32 + q * 8);
      acc[os] = MFMA16(Alo, Bhi, acc[os]);
      acc[os] = MFMA16(Ahi, Blo, acc[os]);
      acc[os] = MFMA16(Ahi, Bhi, acc[os]);
    }
  }
#pragma unroll
  for (int os = 0; os < 4; os++) {
#pragma unroll
    for (int r = 0; r < 4; r++) {
      int o = os * 16 + l15;                 // 0..63 within f or g
      int n = n0 + wr * 16 + q * 4 + r;
      float v = acc[os][r] + (wh == 0 ? bfv[o] : bgv[o]);
      size_t off = ((size_t)((b * 256 + (n >> 4)) * 2 + (o >> 5))) * 512
                 + (((o >> 3) & 3) * 16 + (n & 15)) * 8 + (o & 7);
      short h = f2bf(v);
      short lo = f2bf(v - bf2f(h));
      if (wh == 0) { ffh[off] = h; ffl[off] = lo; }
      else         { gfh[off] = h; gfl[off] = lo; }
    }
  }
}

// ---------------- K_stats: partial l_i = sum_j exp(S) over a 1024-j chunk ----
// Writes per-chunk partial sums to lsum4[chunk][b][i] (no atomics).
__global__ __launch_bounds__(512) void k_stats(
    const short* __restrict__ ffh, const short* __restrict__ ffl,
    const short* __restrict__ gfh, const short* __restrict__ gfl,
    float* __restrict__ lsum4) {
  int jch = blockIdx.x, jc = jch * 1024, i0 = blockIdx.y * 64, b = blockIdx.z;
  int t = threadIdx.x, w = t >> 6, lane = t & 63, l15 = lane & 15, q = lane >> 4;
  bf16x8 Ahi[4][2], Alo[4][2];
#pragma unroll
  for (int ig = 0; ig < 4; ig++)
#pragma unroll
    for (int ss = 0; ss < 2; ss++) {
      size_t base = fg_frag(b, (i0 >> 4) + ig, ss) + lane * 8;
      Ahi[ig][ss] = *(const bf16x8*)(ffh + base);
      Alo[ig][ss] = *(const bf16x8*)(ffl + base);
    }
  float ls[16];
#pragma unroll
  for (int a = 0; a < 16; a++) ls[a] = 0.f;
  f32x4 z = {0.f, 0.f, 0.f, 0.f};
  for (int jt = 0; jt < 8; jt++) {
    int tj = (jc >> 4) + w * 8 + jt;
    bf16x8 GBh[2], GBl[2];
#pragma unroll
    for (int ss = 0; ss < 2; ss++) {
      size_t base = fg_frag(b, tj, ss) + lane * 8;
      GBh[ss] = *(const bf16x8*)(gfh + base);
      GBl[ss] = *(const bf16x8*)(gfl + base);
    }
#pragma unroll
    for (int ig = 0; ig < 4; ig++) {
      f32x4 sh = z, sl = z;
#pragma unroll
      for (int ss = 0; ss < 2; ss++) {
        sl = MFMA16(Alo[ig][ss], GBh[ss], sl);
        sl = MFMA16(Ahi[ig][ss], GBl[ss], sl);
        sh = MFMA16(Ahi[ig][ss], GBh[ss], sh);
      }
#pragma unroll
      for (int r = 0; r < 4; r++) ls[ig * 4 + r] += __expf(sh[r] + sl[r]);
    }
  }
#pragma unroll
  for (int m = 1; m < 16; m <<= 1) {
#pragma unroll
    for (int a = 0; a < 16; a++) ls[a] += __shfl_xor(ls[a], m, 64);
  }
  __shared__ float part[8][64];
  if (l15 == 0) {
#pragma unroll
    for (int ig = 0; ig < 4; ig++)
#pragma unroll
      for (int r = 0; r < 4; r++) part[w][ig * 16 + q * 4 + r] = ls[ig * 4 + r];
  }
  __syncthreads();
  if (t < 64) {
    float s = 0.f;
#pragma unroll
    for (int ww = 0; ww < 8; ww++) s += part[ww][t];
    lsum4[(size_t)jch * 16384 + (size_t)b * Nq + i0 + t] = s;
  }
}

// ---------------- K_hv: hvfrag = frag-packed bf16((Wh.x + bh)/l) ----------------
__global__ __launch_bounds__(512) void k_hv(
    const short* __restrict__ whb, const short* __restrict__ xthi,
    const float* __restrict__ bhv, const float* __restrict__ lsum4,
    short* __restrict__ hvf) {
  int si = blockIdx.x, b = blockIdx.y;
  int t = threadIdx.x, w = t >> 6, lane = t & 63, l15 = lane & 15, q = lane >> 4;
  int c0 = w * 64;
  const short* ar0 = xthi + ((size_t)b * Nq + si * 32 + l15) * Cq;
  const short* ar1 = ar0 + 16 * Cq;
  f32x4 z = {0.f, 0.f, 0.f, 0.f};
  f32x4 acc[2][4];
#pragma unroll
  for (int a = 0; a < 2; a++)
#pragma unroll
    for (int c = 0; c < 4; c++) acc[a][c] = z;
  for (int ks = 0; ks < 16; ks++) {
    bf16x8 A0 = *(const bf16x8*)(ar0 + ks * 32 + q * 8);
    bf16x8 A1 = *(const bf16x8*)(ar1 + ks * 32 + q * 8);
#pragma unroll
    for (int ct = 0; ct < 4; ct++) {
      bf16x8 Bv = *(const bf16x8*)(whb + (size_t)(c0 + ct * 16 + l15) * 512 + ks * 32 + q * 8);
      acc[0][ct] = MFMA16(A0, Bv, acc[0][ct]);
      acc[1][ct] = MFMA16(A1, Bv, acc[1][ct]);
    }
  }
  float li[2][4];
#pragma unroll
  for (int it = 0; it < 2; it++)
#pragma unroll
    for (int r = 0; r < 4; r++) {
      size_t idx = (size_t)b * Nq + si * 32 + it * 16 + q * 4 + r;
      float s = lsum4[idx] + lsum4[16384 + idx] + lsum4[32768 + idx] + lsum4[49152 + idx];
      li[it][r] = 1.0f / s;
    }
  int src0 = ((q & 1) << 5) + l15;
  int src1 = src0 + 16;
  int hiSel = q >> 1;
#pragma unroll
  for (int ct = 0; ct < 4; ct++) {
    float bias = bhv[c0 + ct * 16 + l15];
    unsigned u01[2], u23[2];
#pragma unroll
    for (int it = 0; it < 2; it++) {
      float v0 = (acc[it][ct][0] + bias) * li[it][0];
      float v1 = (acc[it][ct][1] + bias) * li[it][1];
      float v2 = (acc[it][ct][2] + bias) * li[it][2];
      float v3 = (acc[it][ct][3] + bias) * li[it][3];
      u01[it] = (unsigned)(unsigned short)f2bf(v0) | ((unsigned)(unsigned short)f2bf(v1) << 16);
      u23[it] = (unsigned)(unsigned short)f2bf(v2) | ((unsigned)(unsigned short)f2bf(v3) << 16);
    }
    unsigned a0 = __shfl((int)u01[0], src0), b0 = __shfl((int)u01[1], src0);
    unsigned a1 = __shfl((int)u23[0], src0), b1 = __shfl((int)u23[1], src0);
    unsigned a2 = __shfl((int)u01[0], src1), b2 = __shfl((int)u01[1], src1);
    unsigned a3 = __shfl((int)u23[0], src1), b3 = __shfl((int)u23[1], src1);
    uint4 st;
    st.x = hiSel ? b0 : a0;
    st.y = hiSel ? b1 : a1;
    st.z = hiSel ? b2 : a2;
    st.w = hiSel ? b3 : a3;
    *(uint4*)(hvf + hv_frag(b, (c0 >> 4) + ct, si) + (size_t)lane * 8) = st;
  }
}

// ---------------- K_attn: out = gamma * hv2 @ exp(S) + x ----------------
// 256 blocks (b x j-tile 64), 512 thr. S roles: wave = (iq = w&3) x (jh = w>>2).
// PV roles: wave owns c-strip w*64, all 64 j. 44 MFMA/wave-iter.
// P^T [64 j][64 i] in LDS (stride 72), dbuf, 1 barrier/iter.
__global__ __launch_bounds__(512, 2) void k_attn(
    const short* __restrict__ ffh, const short* __restrict__ ffl,
    const short* __restrict__ gfh, const short* __restrict__ gfl,
    const short* __restrict__ hvf, const float* __restrict__ x,
    const float* __restrict__ gp, float* __restrict__ out) {
  int L = blockIdx.x;
  int b = (L & 7) >> 1;                   // batch -> XCD pair
  int jt64 = ((L >> 3) << 1) | (L & 1);   // 0..63
  int j0 = jt64 * 64;
  int t = threadIdx.x, w = t >> 6, lane = t & 63, l15 = lane & 15, q = lane >> 4;
  int iq = w & 3, jh = w >> 2;            // S roles
  __shared__ __align__(16) short pt[2][64 * PSTR];   // 18.4 KB
  float gamma = gp[0];
  f32x4 z = {0.f, 0.f, 0.f, 0.f};
  f32x4 acc[4][4];                        // [ct][jt]
#pragma unroll
  for (int a = 0; a < 4; a++)
#pragma unroll
    for (int bb = 0; bb < 4; bb++) acc[a][bb] = z;
  // Hoist g frags for this wave's S j-half (2 tiles of 16 j).
  bf16x8 GBh[2][2], GBl[2][2];
#pragma unroll
  for (int jt = 0; jt < 2; jt++)
#pragma unroll
    for (int ss = 0; ss < 2; ss++) {
      size_t base = fg_frag(b, (j0 >> 4) + jh * 2 + jt, ss) + lane * 8;
      GBh[jt][ss] = *(const bf16x8*)(gfh + base);
      GBl[jt][ss] = *(const bf16x8*)(gfl + base);
    }

  auto computeS = [&](int it, int buf) {
    bf16x8 Ah[2], Al[2];
#pragma unroll
    for (int ss = 0; ss < 2; ss++) {
      size_t base = fg_frag(b, it * 4 + iq, ss) + lane * 8;
      Ah[ss] = *(const bf16x8*)(ffh + base);
      Al[ss] = *(const bf16x8*)(ffl + base);
    }
#pragma unroll
    for (int jt = 0; jt < 2; jt++) {
      f32x4 sh = z, sl = z;
#pragma unroll
      for (int ss = 0; ss < 2; ss++) {
        sl = MFMA16(Al[ss], GBh[jt][ss], sl);
        sl = MFMA16(Ah[ss], GBl[jt][ss], sl);
        sh = MFMA16(Ah[ss], GBh[jt][ss], sh);
      }
      unsigned p01 = (unsigned)(unsigned short)f2bf(__expf(sh[0] + sl[0])) |
                     ((unsigned)(unsigned short)f2bf(__expf(sh[1] + sl[1])) << 16);
      unsigned p23 = (unsigned)(unsigned short)f2bf(__expf(sh[2] + sl[2])) |
                     ((unsigned)(unsigned short)f2bf(__expf(sh[3] + sl[3])) << 16);
      uint2 pv; pv.x = p01; pv.y = p23;
      *(uint2*)(&pt[buf][(jh * 32 + jt * 16 + l15) * PSTR + iq * 16 + q * 4]) = pv;
    }
  };

  computeS(0, 0);
  for (int it = 0; it < 64; it++) {
    __syncthreads();
    int buf = it & 1;
    if (it < 63) computeS(it + 1, 1 - buf);
#pragma unroll
    for (int ss = 0; ss < 2; ss++) {
      bf16x8 PB[4];
#pragma unroll
      for (int jt = 0; jt < 4; jt++)
        PB[jt] = *(const bf16x8*)(&pt[buf][(jt * 16 + l15) * PSTR + ss * 32 + q * 8]);
#pragma unroll
      for (int ct = 0; ct < 4; ct++) {
        size_t hb = hv_frag(b, w * 4 + ct, it * 2 + ss) + lane * 8;
        bf16x8 A = *(const bf16x8*)(hvf + hb);
#pragma unroll
        for (int jt = 0; jt < 4; jt++)
          acc[ct][jt] = MFMA16(A, PB[jt], acc[ct][jt]);
      }
    }
  }
#pragma unroll
  for (int ct = 0; ct < 4; ct++) {
#pragma unroll
    for (int jt = 0; jt < 4; jt++) {
#pragma unroll
      for (int r = 0; r < 4; r++) {
        int c = w * 64 + ct * 16 + q * 4 + r;
        int j = j0 + jt * 16 + l15;
        size_t off = ((size_t)b * Cq + c) * Nq + j;
        out[off] = gamma * acc[ct][jt][r] + x[off];
      }
    }
  }
}

extern "C" void kernel_launch(void* const* d_in, const int* in_sizes, int n_in,
                              void* d_out, int out_size, void* d_ws, size_t ws_size,
                              hipStream_t stream) {
  (void)in_sizes; (void)n_in; (void)out_size; (void)ws_size;
  const float* x  = (const float*)d_in[0];
  const float* Wf = (const float*)d_in[1];
  const float* bf = (const float*)d_in[2];
  const float* Wg = (const float*)d_in[3];
  const float* bg = (const float*)d_in[4];
  const float* Wh = (const float*)d_in[5];
  const float* bh = (const float*)d_in[6];
  const float* gm = (const float*)d_in[7];
  float* out = (float*)d_out;
  char* ws = (char*)d_ws;
  // Workspace layout (bytes); total 59,768,832 (~57 MB)
  short* xthi  = (short*)(ws);               // 16,777,216  (B,N,C) bf16 hi
  short* xtlo  = (short*)(ws + 16777216);    // 16,777,216  lo
  short* ffh   = (short*)(ws + 33554432);    //  2,097,152  f frag-packed hi
  short* ffl   = (short*)(ws + 35651584);    //  2,097,152  f lo
  short* gfh   = (short*)(ws + 37748736);    //  2,097,152  g frag-packed hi
  short* gfl   = (short*)(ws + 39845888);    //  2,097,152  g lo
  short* whi   = (short*)(ws + 41943040);    //    131,072  (128,512)
  short* wlo   = (short*)(ws + 42074112);    //    131,072
  short* whb   = (short*)(ws + 42205184);    //    524,288  (512,512)
  float* lsum4 = (float*)(ws + 42729472);    //    262,144  (4 chunks, B, N)
  short* hvf   = (short*)(ws + 42991616);    // 16,777,216  hv frag-packed bf16

  hipLaunchKernelGGL(k_prepw, dim3(1024), dim3(256), 0, stream, Wf, Wg, Wh, whi, wlo, whb);
  hipLaunchKernelGGL(k_xpose, dim3(64, 8, 4), dim3(256), 0, stream, x, xthi, xtlo);
  hipLaunchKernelGGL(k_fg, dim3(64, 4), dim3(512), 0, stream,
                     xthi, xtlo, whi, wlo, bf, bg, ffh, ffl, gfh, gfl);
  hipLaunchKernelGGL(k_stats, dim3(4, 64, 4), dim3(512), 0, stream, ffh, ffl, gfh, gfl, lsum4);
  hipLaunchKernelGGL(k_hv, dim3(128, 4), dim3(512), 0, stream, whb, xthi, bh, lsum4, hvf);
  hipLaunchKernelGGL(k_attn, dim3(256), dim3(512), 0, stream,
                     ffh, ffl, gfh, gfl, hvf, x, gm, out);
}